// Round 1
// baseline (4953.161 us; speedup 1.0000x reference)
//
#include <hip/hip_runtime.h>
#include <cmath>

// Problem constants
#define T_STEPS 512
#define BATCH   64
#define HID     1024
#define INSZ    128
#define ESZ     819
#define OSZ     64

// ws layout (floats):
//  eff_w  [1024*1024]                 @ 0
//  w_ihT  [128*1024]                  @ 1048576
//  hist   [64][512][1024]  ([b][t][h])@ 1179648   (zero-init each launch; values stored TAGGED = ov+2)
//  badj   [64]  (fc bias adjusted)    @ 34734080  (old flags region, flags no longer needed)
//  w_fcp  [64*820] (padded w_fc)      @ 34742272
#define WS_EFFW   0
#define WS_WIHT   1048576
#define WS_HIST   1179648
#define WS_BADJ   34734080
#define WS_WFCP   34742272

typedef float f32x4 __attribute__((ext_vector_type(4)));

// ---------------- prep kernels ----------------
__global__ void prep_effw(const float* __restrict__ w_hh, const float* __restrict__ mask,
                          float* __restrict__ eff) {
    const int i = (blockIdx.x * 256 + threadIdx.x) * 4;
    const float4 w = *(const float4*)(w_hh + i);
    const float4 m = *(const float4*)(mask + i);
    float4 r;
    r.x = fabsf(w.x) * m.x; r.y = fabsf(w.y) * m.y;
    r.z = fabsf(w.z) * m.z; r.w = fabsf(w.w) * m.w;
    *(float4*)(eff + i) = r;
}

__global__ void prep_wihT(const float* __restrict__ w_ih, float* __restrict__ w_ihT) {
    const int idx = blockIdx.x * 256 + threadIdx.x;   // idx = i*1024 + h
    const int i = idx >> 10, h = idx & 1023;
    w_ihT[idx] = w_ih[h * INSZ + i];
}

// pad w_fc AND compute badj[o] = b_fc[o] - 2*sum_e w_fc[o][e]
// (hist holds tagged values h+2; sum_e w*(h+2) = sum w*h + 2*sum w -> fold into bias)
__global__ void prep_wfc(const float* __restrict__ w_fc, const float* __restrict__ b_fc,
                         float* __restrict__ w_fcp, float* __restrict__ badj) {
    __shared__ float red[256];
    const int o = blockIdx.x, tid = threadIdx.x;
    float s = 0.f;
    for (int e = tid; e < 820; e += 256) {
        const float w = (e < ESZ) ? w_fc[o * ESZ + e] : 0.f;
        w_fcp[o * 820 + e] = w;
        s += w;
    }
    red[tid] = s;
    __syncthreads();
    for (int st = 128; st; st >>= 1) {
        if (tid < st) red[tid] += red[tid + st];
        __syncthreads();
    }
    if (tid == 0) badj[o] = b_fc[o] - 2.0f * red[0];
}

// ---------------- input projection: u[b][t][h] = x[t,b,:]@w_ih[h,:] + b_ih[h] ----------------
__global__ void inp_proj(const float* __restrict__ x, const float* __restrict__ w_ihT,
                         const float* __restrict__ b_ih, float* __restrict__ u) {
    __shared__ float xs[INSZ * 64];   // [i][b], 32 KB
    const int t = blockIdx.x, tid = threadIdx.x;
    const float* xt = x + (size_t)t * BATCH * INSZ;
    for (int k = tid * 4; k < BATCH * INSZ; k += 1024) {
        const float4 v = *(const float4*)(xt + k);
        const int b = k >> 7, i = k & 127;
        xs[(i + 0) * 64 + b] = v.x; xs[(i + 1) * 64 + b] = v.y;
        xs[(i + 2) * 64 + b] = v.z; xs[(i + 3) * 64 + b] = v.w;
    }
    __syncthreads();
    for (int hp = 0; hp < 2; ++hp) {
        const int h = hp * 512 + tid * 2;
        const float bi0 = b_ih[h], bi1 = b_ih[h + 1];
        for (int b0 = 0; b0 < 64; b0 += 8) {
            float acc0[8], acc1[8];
#pragma unroll
            for (int bb = 0; bb < 8; ++bb) { acc0[bb] = 0.f; acc1[bb] = 0.f; }
#pragma unroll 4
            for (int i = 0; i < INSZ; ++i) {
                const float2 w2 = *(const float2*)(w_ihT + i * 1024 + h);
                const float4 xa = *(const float4*)(xs + i * 64 + b0);
                const float4 xb = *(const float4*)(xs + i * 64 + b0 + 4);
                const float xv[8] = {xa.x, xa.y, xa.z, xa.w, xb.x, xb.y, xb.z, xb.w};
#pragma unroll
                for (int bb = 0; bb < 8; ++bb) {
                    acc0[bb] = fmaf(w2.x, xv[bb], acc0[bb]);
                    acc1[bb] = fmaf(w2.y, xv[bb], acc1[bb]);
                }
            }
#pragma unroll
            for (int bb = 0; bb < 8; ++bb) {
                float2 r; r.x = acc0[bb] + bi0; r.y = acc1[bb] + bi1;
                *(float2*)(u + ((size_t)(b0 + bb) * T_STEPS + t) * 1024 + h) = r;
            }
        }
    }
}

// 8 x 16B loads + single drain, one self-contained asm block (values valid at asm end).
// SFX selects cache scope: " sc0" = bypass L1, read XCD L2 (fast when writer co-XCD);
// " sc0 sc1" = read Infinity Cache directly (always sees agent-scope stores -> no livelock).
#define LOAD8(SFX)                                                       \
    asm volatile("global_load_dwordx4 %0, %8, off" SFX "\n\t"            \
                 "global_load_dwordx4 %1, %8, off offset:16" SFX "\n\t"  \
                 "global_load_dwordx4 %2, %8, off offset:32" SFX "\n\t"  \
                 "global_load_dwordx4 %3, %8, off offset:48" SFX "\n\t"  \
                 "global_load_dwordx4 %4, %8, off offset:64" SFX "\n\t"  \
                 "global_load_dwordx4 %5, %8, off offset:80" SFX "\n\t"  \
                 "global_load_dwordx4 %6, %8, off offset:96" SFX "\n\t"  \
                 "global_load_dwordx4 %7, %8, off offset:112" SFX "\n\t" \
                 "s_waitcnt vmcnt(0)"                                    \
                 : "=&v"(v0), "=&v"(v1), "=&v"(v2), "=&v"(v3),           \
                   "=&v"(v4), "=&v"(v5), "=&v"(v6), "=&v"(v7)            \
                 : "v"(src) : "memory")

__device__ __forceinline__ float vmin4f(f32x4 v) {
    return fminf(fminf(v[0], v[1]), fminf(v[2], v[3]));
}

#define MIN32()                                                              \
    fminf(fminf(fminf(vmin4f(v0), vmin4f(v1)), fminf(vmin4f(v2), vmin4f(v3))), \
          fminf(fminf(vmin4f(v4), vmin4f(v5)), fminf(vmin4f(v6), vmin4f(v7))))

// ---------------- persistent recurrent scan (cooperative) ----------------
// grid 256 WGs x 256 thr; WG = (bg = blk&7 -> 8 batches, hgrp = blk>>3 -> 32 hidden rows)
// Sync protocol: NO flags. hist zero-initialized; writers store (tanh+2) agent-scope
// (write-through L2 + IC). tanh in [-1,1] -> tagged value in [1,3]; unwritten = 0.
// Readers poll their exact 32-float slice: first try sc0 (XCD-L2; bg==wg&7 matches the
// round-robin block->XCD mapping so partners are usually co-XCD), escalate to sc0+sc1 (IC)
// if stale -- correct regardless of placement. The +2 tag is folded into bias_eff.
// LDS: w_s 32768 floats (swizzled [j][hl]) + pp 8192 floats (prev[8][1024] | part[256][32])
__global__ void __launch_bounds__(256, 1)
rnn_scan(const float* __restrict__ eff_w, const float* __restrict__ u,
         const float* __restrict__ b_hh, const float* __restrict__ alpha,
         float* __restrict__ hist) {
    extern __shared__ float smem[];
    float* w_s = smem;            // 32768
    float* pp  = smem + 32768;    // 8192
    const int tid = threadIdx.x, wg = blockIdx.x;
    const int bg = wg & 7, hgrp = wg >> 3;
    const int h0 = hgrp << 5, b0 = bg << 3;

    float rsum = 0.f;
    { // load 32 weight rows, swizzled: logical w[j][hl] -> phys j*32 + (((hl>>2)+j)&7)*4 + (hl&3)
      // also accumulate row sum (for the +2-tag bias fold)
        const int hl = tid >> 3, grp = hl >> 2, l4 = hl & 3;
        const int j0 = (tid & 7) << 7;
        const float* wrow = eff_w + (size_t)(h0 + hl) * 1024;
        for (int j = j0; j < j0 + 128; j += 4) {
            const float4 w4 = *(const float4*)(wrow + j);
            w_s[((j + 0) << 5) + (((grp + j + 0) & 7) << 2) + l4] = w4.x;
            w_s[((j + 1) << 5) + (((grp + j + 1) & 7) << 2) + l4] = w4.y;
            w_s[((j + 2) << 5) + (((grp + j + 2) & 7) << 2) + l4] = w4.z;
            w_s[((j + 3) << 5) + (((grp + j + 3) & 7) << 2) + l4] = w4.w;
            rsum += (w4.x + w4.y) + (w4.z + w4.w);
        }
    }
    // 8 loader threads (tid^{1,2,4}) share one row hl = tid>>3 == compute r_hl -> full row sum
    rsum += __shfl_xor(rsum, 1);
    rsum += __shfl_xor(rsum, 2);
    rsum += __shfl_xor(rsum, 4);

    const float a = alpha[0];
    const int r_hl = tid >> 3, r_b = tid & 7;
    const int rh = h0 + r_hl, rb = b0 + r_b;
    const float bias0 = b_hh[rh];
    const float bias_eff = bias0 - 2.0f * rsum;   // cancels the +2 tag: sum w*(p+2) - 2*sum w
    const size_t u_base = ((size_t)rb * T_STEPS) * 1024 + rh;
    float* const my_hist = hist + ((size_t)rb * T_STEPS) * 1024 + rh;
    const int hp = tid >> 5, jc = tid & 31;         // compute role: 4h x 8b tile, j-slice
    const int sb = tid >> 5, sj = (tid & 31) << 5;  // staging role: one 32-float row
    const float* const src_base = hist + ((size_t)(b0 + sb) * T_STEPS) * 1024 + sj;
    const int rot = tid & 7;                        // staging LDS rotation (bank-conflict-free)
    float state = 0.f;
    __syncthreads();

    for (int t = 0; t < T_STEPS; ++t) {
        const float uval = u[u_base + ((size_t)t << 10)];  // prefetch early (in flight during poll)
        float red = 0.f;
        if (t > 0) {
            // ---- poll + stage prev output slice (tagged data IS the sync) ----
            f32x4 v0, v1, v2, v3, v4, v5, v6, v7;
            const float* src = src_base + ((size_t)(t - 1) << 10);
            LOAD8(" sc0");
            float mn = MIN32();
            while (!(mn >= 1.0f)) {            // any value < 1 -> not yet written
                __builtin_amdgcn_s_sleep(1);
                LOAD8(" sc0 sc1");             // IC read: immune to stale local-L2 fills
                mn = MIN32();
            }
            // rotated chunk placement: chunk k -> slot (k+tid)&7 -> 32 distinct banks/phase
            float* dst = pp + (sb << 10) + sj;
            *(f32x4*)(dst + (((rot + 0) & 7) << 2)) = v0;
            *(f32x4*)(dst + (((rot + 1) & 7) << 2)) = v1;
            *(f32x4*)(dst + (((rot + 2) & 7) << 2)) = v2;
            *(f32x4*)(dst + (((rot + 3) & 7) << 2)) = v3;
            *(f32x4*)(dst + (((rot + 4) & 7) << 2)) = v4;
            *(f32x4*)(dst + (((rot + 5) & 7) << 2)) = v5;
            *(f32x4*)(dst + (((rot + 6) & 7) << 2)) = v6;
            *(f32x4*)(dst + (((rot + 7) & 7) << 2)) = v7;
            __syncthreads();

            float acc[4][8];
#pragma unroll
            for (int i = 0; i < 4; ++i)
#pragma unroll
                for (int b = 0; b < 8; ++b) acc[i][b] = 0.f;
#pragma unroll 2
            for (int jj = 0; jj < 32; ++jj) {
                const int j = (jj << 5) + jc;
                const f32x4 wv = *(const f32x4*)&w_s[(j << 5) + (((hp + j) & 7) << 2)];
                // inverse of the staging rotation: phys offset of logical prev[b][j]
                const int phij = (jj << 5) + ((((jj * 9) + (jc >> 2)) & 7) << 2) + (jc & 3);
                float pv[8];
#pragma unroll
                for (int b = 0; b < 8; ++b) pv[b] = pp[(b << 10) + phij];  // broadcast reads
#pragma unroll
                for (int b = 0; b < 8; ++b) {
                    acc[0][b] = fmaf(wv[0], pv[b], acc[0][b]);
                    acc[1][b] = fmaf(wv[1], pv[b], acc[1][b]);
                    acc[2][b] = fmaf(wv[2], pv[b], acc[2][b]);
                    acc[3][b] = fmaf(wv[3], pv[b], acc[3][b]);
                }
            }
            __syncthreads();   // prev consumed; reuse pp as partial buffer
#pragma unroll
            for (int i = 0; i < 4; ++i)
#pragma unroll
                for (int b = 0; b < 8; ++b) {
                    const int oo = ((hp << 2) + i) * 8 + b;
                    pp[(oo << 5) + ((jc + oo) & 31)] = acc[i][b];   // rotated: conflict-free
                }
            __syncthreads();
#pragma unroll
            for (int k = 0; k < 32; ++k)
                red += pp[(tid << 5) + ((k + tid) & 31)];
        }
        const float tot = uval + red + ((t > 0) ? bias_eff : bias0);
        state = fmaf(a, tot - state, state);
        const float ov = tanhf(state);
        // tagged write-through store (L2 + IC): both the data AND the sync signal.
        // no drain, no flag, no spin -- readers poll the data directly.
        __hip_atomic_store(my_hist + ((size_t)t << 10), ov + 2.0f, __ATOMIC_RELAXED,
                           __HIP_MEMORY_SCOPE_AGENT);
        __syncthreads();   // protects pp: reduce-reads (this t) vs stage-writes (t+1)
    }
}

// ---------------- rnn_activity copy: act[t][b][h] = hist[b][t][h] - 2 (untag) ----------------
__global__ void copy_act(const float* __restrict__ hist, float* __restrict__ act) {
    const int t = blockIdx.x >> 6, b = blockIdx.x & 63;
    const float* src = hist + ((size_t)b * T_STEPS + t) * 1024 + threadIdx.x * 4;
    float* dst = act + ((size_t)t * BATCH + b) * 1024 + threadIdx.x * 4;
    float4 v = *(const float4*)src;
    v.x -= 2.0f; v.y -= 2.0f; v.z -= 2.0f; v.w -= 2.0f;
    *(float4*)dst = v;
}

// ---------------- final FC: out0[t][b][o] = (hist-2)[b][t][:819]@w_fc[o,:] + b_fc[o] ----------
// hist holds tagged h+2; badj[o] = b_fc[o] - 2*sum_e w_fc[o][e] makes this exact.
__global__ void fc_out(const float* __restrict__ hist, const float* __restrict__ w_fcp,
                       const float* __restrict__ badj, float* __restrict__ out0) {
    __shared__ float hs[16 * 820];   // 52.5 KB
    const int t = blockIdx.x >> 2, bq = blockIdx.x & 3, tid = threadIdx.x;
    const int b0 = bq << 4;
    for (int r = 0; r < 16; ++r) {
        const float* src = hist + ((size_t)(b0 + r) * T_STEPS + t) * 1024;
        for (int e = tid; e < 820; e += 256) hs[r * 820 + e] = (e < ESZ) ? src[e] : 0.f;
    }
    __syncthreads();
    const int bb = tid >> 4, ol = tid & 15;
    float acc[4] = {0.f, 0.f, 0.f, 0.f};
    const float* hrow = hs + bb * 820;
    for (int e = 0; e < 820; e += 4) {
        const float4 hv = *(const float4*)(hrow + e);
#pragma unroll
        for (int k = 0; k < 4; ++k) {
            const float4 wv = *(const float4*)(w_fcp + (size_t)(ol + (k << 4)) * 820 + e);
            acc[k] += hv.x * wv.x + hv.y * wv.y + hv.z * wv.z + hv.w * wv.w;
        }
    }
    const int b = b0 + bb;
#pragma unroll
    for (int k = 0; k < 4; ++k) {
        const int o = ol + (k << 4);
        out0[((size_t)t * BATCH + b) * OSZ + o] = acc[k] + badj[o];
    }
}

extern "C" void kernel_launch(void* const* d_in, const int* in_sizes, int n_in,
                              void* d_out, int out_size, void* d_ws, size_t ws_size,
                              hipStream_t stream) {
    const float* x     = (const float*)d_in[0];
    const float* w_ih  = (const float*)d_in[1];
    const float* b_ih  = (const float*)d_in[2];
    const float* w_hh  = (const float*)d_in[3];
    const float* b_hh  = (const float*)d_in[4];
    const float* w_fc  = (const float*)d_in[5];
    const float* b_fc  = (const float*)d_in[6];
    const float* alpha = (const float*)d_in[7];
    const float* mask  = (const float*)d_in[8];

    float* out  = (float*)d_out;
    float* out0 = out;                                 // [512][64][64]
    float* act  = out + (size_t)T_STEPS * BATCH * OSZ; // [512][64][1024]

    float* ws     = (float*)d_ws;
    float* eff_w  = ws + WS_EFFW;
    float* w_ihT  = ws + WS_WIHT;
    float* hist   = ws + WS_HIST;
    float* badj   = ws + WS_BADJ;
    float* w_fcp  = ws + WS_WFCP;
    float* u      = act;   // inp_proj lives in d_out's activity region ([b][t][h]), overwritten later

    // hist must be zero so the [1,3]-range tag test distinguishes written from unwritten.
    hipMemsetAsync(hist, 0, (size_t)BATCH * T_STEPS * HID * sizeof(float), stream);
    prep_effw<<<1024, 256, 0, stream>>>(w_hh, mask, eff_w);
    prep_wihT<<<512, 256, 0, stream>>>(w_ih, w_ihT);
    prep_wfc<<<64, 256, 0, stream>>>(w_fc, b_fc, w_fcp, badj);
    inp_proj<<<512, 256, 0, stream>>>(x, w_ihT, b_ih, u);

    hipFuncSetAttribute(reinterpret_cast<const void*>(rnn_scan),
                        hipFuncAttributeMaxDynamicSharedMemorySize, 163840);
    void* args[] = {(void*)&eff_w, (void*)&u, (void*)&b_hh, (void*)&alpha, (void*)&hist};
    hipLaunchCooperativeKernel(reinterpret_cast<const void*>(rnn_scan),
                               dim3(256), dim3(256), args, 163840, stream);

    copy_act<<<32768, 256, 0, stream>>>(hist, act);
    fc_out<<<2048, 256, 0, stream>>>(hist, w_fcp, badj, out0);
}

// Round 2
// 4176.693 us; speedup vs baseline: 1.1859x; 1.1859x over previous
//
#include <hip/hip_runtime.h>
#include <cmath>

// Problem constants
#define T_STEPS 512
#define BATCH   64
#define HID     1024
#define INSZ    128
#define ESZ     819
#define OSZ     64

// ws layout (floats):
//  eff_w  [1024*1024]                 @ 0
//  w_ihT  [128*1024]                  @ 1048576
//  hist   [64][512][1024]  ([b][t][h])@ 1179648   (zero-init each launch; values stored TAGGED = ov+2)
//  badj   [64]  (fc bias adjusted)    @ 34734080
//  w_fcp  [64*820] (padded w_fc)      @ 34742272
#define WS_EFFW   0
#define WS_WIHT   1048576
#define WS_HIST   1179648
#define WS_BADJ   34734080
#define WS_WFCP   34742272

typedef float f32x4 __attribute__((ext_vector_type(4)));

// ---------------- prep kernels ----------------
__global__ void prep_effw(const float* __restrict__ w_hh, const float* __restrict__ mask,
                          float* __restrict__ eff) {
    const int i = (blockIdx.x * 256 + threadIdx.x) * 4;
    const float4 w = *(const float4*)(w_hh + i);
    const float4 m = *(const float4*)(mask + i);
    float4 r;
    r.x = fabsf(w.x) * m.x; r.y = fabsf(w.y) * m.y;
    r.z = fabsf(w.z) * m.z; r.w = fabsf(w.w) * m.w;
    *(float4*)(eff + i) = r;
}

__global__ void prep_wihT(const float* __restrict__ w_ih, float* __restrict__ w_ihT) {
    const int idx = blockIdx.x * 256 + threadIdx.x;   // idx = i*1024 + h
    const int i = idx >> 10, h = idx & 1023;
    w_ihT[idx] = w_ih[h * INSZ + i];
}

// pad w_fc AND compute badj[o] = b_fc[o] - 2*sum_e w_fc[o][e]
__global__ void prep_wfc(const float* __restrict__ w_fc, const float* __restrict__ b_fc,
                         float* __restrict__ w_fcp, float* __restrict__ badj) {
    __shared__ float red[256];
    const int o = blockIdx.x, tid = threadIdx.x;
    float s = 0.f;
    for (int e = tid; e < 820; e += 256) {
        const float w = (e < ESZ) ? w_fc[o * ESZ + e] : 0.f;
        w_fcp[o * 820 + e] = w;
        s += w;
    }
    red[tid] = s;
    __syncthreads();
    for (int st = 128; st; st >>= 1) {
        if (tid < st) red[tid] += red[tid + st];
        __syncthreads();
    }
    if (tid == 0) badj[o] = b_fc[o] - 2.0f * red[0];
}

// ---------------- input projection: u[b][t][h] = x[t,b,:]@w_ih[h,:] + b_ih[h] ----------------
__global__ void inp_proj(const float* __restrict__ x, const float* __restrict__ w_ihT,
                         const float* __restrict__ b_ih, float* __restrict__ u) {
    __shared__ float xs[INSZ * 64];   // [i][b], 32 KB
    const int t = blockIdx.x, tid = threadIdx.x;
    const float* xt = x + (size_t)t * BATCH * INSZ;
    for (int k = tid * 4; k < BATCH * INSZ; k += 1024) {
        const float4 v = *(const float4*)(xt + k);
        const int b = k >> 7, i = k & 127;
        xs[(i + 0) * 64 + b] = v.x; xs[(i + 1) * 64 + b] = v.y;
        xs[(i + 2) * 64 + b] = v.z; xs[(i + 3) * 64 + b] = v.w;
    }
    __syncthreads();
    for (int hp = 0; hp < 2; ++hp) {
        const int h = hp * 512 + tid * 2;
        const float bi0 = b_ih[h], bi1 = b_ih[h + 1];
        for (int b0 = 0; b0 < 64; b0 += 8) {
            float acc0[8], acc1[8];
#pragma unroll
            for (int bb = 0; bb < 8; ++bb) { acc0[bb] = 0.f; acc1[bb] = 0.f; }
#pragma unroll 4
            for (int i = 0; i < INSZ; ++i) {
                const float2 w2 = *(const float2*)(w_ihT + i * 1024 + h);
                const float4 xa = *(const float4*)(xs + i * 64 + b0);
                const float4 xb = *(const float4*)(xs + i * 64 + b0 + 4);
                const float xv[8] = {xa.x, xa.y, xa.z, xa.w, xb.x, xb.y, xb.z, xb.w};
#pragma unroll
                for (int bb = 0; bb < 8; ++bb) {
                    acc0[bb] = fmaf(w2.x, xv[bb], acc0[bb]);
                    acc1[bb] = fmaf(w2.y, xv[bb], acc1[bb]);
                }
            }
#pragma unroll
            for (int bb = 0; bb < 8; ++bb) {
                float2 r; r.x = acc0[bb] + bi0; r.y = acc1[bb] + bi1;
                *(float2*)(u + ((size_t)(b0 + bb) * T_STEPS + t) * 1024 + h) = r;
            }
        }
    }
}

// ---- per-chunk staged-exchange primitives ----
// ISSUE2: fire 2 x 16B loads (no wait) -- latency hides under previous chunk's FMA.
// WAIT2:  drain; ties the in-flight regs so the compiler can't touch them early.
// RELOAD2: retry path, reads Infinity Cache directly (sc0 sc1) -- placement-proof.
#define ISSUE2(VA, VB, SRC)                                               \
    asm volatile("global_load_dwordx4 %0, %2, off sc0\n\t"                \
                 "global_load_dwordx4 %1, %2, off offset:512 sc0"         \
                 : "=&v"(VA), "=&v"(VB) : "v"(SRC) : "memory")
#define WAIT2(VA, VB)                                                     \
    asm volatile("s_waitcnt vmcnt(0)" : "+v"(VA), "+v"(VB) :: "memory")
#define RELOAD2(VA, VB, SRC)                                              \
    asm volatile("global_load_dwordx4 %0, %2, off sc0 sc1\n\t"            \
                 "global_load_dwordx4 %1, %2, off offset:512 sc0 sc1\n\t" \
                 "s_waitcnt vmcnt(0)"                                     \
                 : "=&v"(VA), "=&v"(VB) : "v"(SRC) : "memory")

__device__ __forceinline__ float min8f(f32x4 x, f32x4 y) {
    return fminf(fminf(fminf(x[0], x[1]), fminf(x[2], x[3])),
                 fminf(fminf(y[0], y[1]), fminf(y[2], y[3])));
}

// ---------------- persistent recurrent scan (cooperative) ----------------
// grid 256 WGs x 256 thr; WG = (bg = blk&7 -> 8 batches, hgrp = blk>>3 -> 32 hidden rows)
// Tag-in-data sync (hist zeroed, stored value = tanh+2 in [1,3], unwritten = 0), with
// CHUNK-PIPELINED exchange: j in 4 chunks of 256; per chunk each thread polls/stages its
// 8 floats, then FMAs that chunk while the next chunk's loads are in flight. Chunk order
// is rotated so the WG's own (stalest) h-range is polled last. pp uses swizzle
// phi(j) = (j&~31) | ((((j>>2)+(j>>5))&7)<<2) | (j&3)  -- bank-balanced for both the
// dwordx4 staging writes and the per-b broadcast FMA reads.
// LDS: w_s 32768 floats (swizzled [j][hl]) + pp 8192 floats (prev[8][1024] | part[256][32])
__global__ void __launch_bounds__(256, 1)
rnn_scan(const float* __restrict__ eff_w, const float* __restrict__ u,
         const float* __restrict__ b_hh, const float* __restrict__ alpha,
         float* __restrict__ hist) {
    extern __shared__ float smem[];
    float* w_s = smem;            // 32768
    float* pp  = smem + 32768;    // 8192
    const int tid = threadIdx.x, wg = blockIdx.x;
    const int bg = wg & 7, hgrp = wg >> 3;
    const int h0 = hgrp << 5, b0 = bg << 3;

    float rsum = 0.f;
    { // load 32 weight rows, swizzled: logical w[j][hl] -> phys j*32 + (((hl>>2)+j)&7)*4 + (hl&3)
        const int hl = tid >> 3, grp = hl >> 2, l4 = hl & 3;
        const int j0 = (tid & 7) << 7;
        const float* wrow = eff_w + (size_t)(h0 + hl) * 1024;
        for (int j = j0; j < j0 + 128; j += 4) {
            const float4 w4 = *(const float4*)(wrow + j);
            w_s[((j + 0) << 5) + (((grp + j + 0) & 7) << 2) + l4] = w4.x;
            w_s[((j + 1) << 5) + (((grp + j + 1) & 7) << 2) + l4] = w4.y;
            w_s[((j + 2) << 5) + (((grp + j + 2) & 7) << 2) + l4] = w4.z;
            w_s[((j + 3) << 5) + (((grp + j + 3) & 7) << 2) + l4] = w4.w;
            rsum += (w4.x + w4.y) + (w4.z + w4.w);
        }
    }
    rsum += __shfl_xor(rsum, 1);
    rsum += __shfl_xor(rsum, 2);
    rsum += __shfl_xor(rsum, 4);

    const float a = alpha[0];
    const int r_hl = tid >> 3, r_b = tid & 7;
    const int rh = h0 + r_hl, rb = b0 + r_b;
    const float bias0 = b_hh[rh];
    const float bias_eff = bias0 - 2.0f * rsum;   // cancels the +2 tag
    const size_t u_base = ((size_t)rb * T_STEPS) * 1024 + rh;
    float* const my_hist = hist + ((size_t)rb * T_STEPS) * 1024 + rh;
    const int hp = tid >> 5, jc = tid & 31;         // compute role
    const int b_s = tid >> 5, q = tid & 31;         // staging role: 8 floats per chunk
    const float* const sbase = hist + ((size_t)(b0 + b_s) * T_STEPS) * 1024 + (q << 2);
    // chunk-invariant LDS phys offsets of the thread's two staged 16B pieces (swizzle phi)
    const int s1 = ((q & 7) + (q >> 3)) & 7;
    const int s2 = (s1 + 4) & 7;
    const int ppA = (b_s << 10) + ((q >> 3) << 5) + (s1 << 2);
    const int ppB = (b_s << 10) + 128 + ((q >> 3) << 5) + (s2 << 2);
    const int cbase = ((hgrp >> 3) + 1) & 3;        // own chunk processed LAST
    float state = 0.f;
    f32x4 vA, vB;
    __syncthreads();

    for (int t = 0; t < T_STEPS; ++t) {
        const float uval = u[u_base + ((size_t)t << 10)];  // issued early, used at step end
        float red = 0.f;
        if (t > 0) {
            const float* srow = sbase + ((size_t)(t - 1) << 10);
            float acc[4][8];
#pragma unroll
            for (int i = 0; i < 4; ++i)
#pragma unroll
                for (int b = 0; b < 8; ++b) acc[i][b] = 0.f;

            int cc = cbase;
            for (int k = 0; k < 4; ++k) {
                // ---- stage chunk cc (loads already in flight) ----
                {
                    const float* sc = srow + (cc << 8);
                    WAIT2(vA, vB);
                    float mn = min8f(vA, vB);
                    while (!(mn >= 1.0f)) {            // any value < 1 -> not yet written
                        __builtin_amdgcn_s_sleep(1);
                        RELOAD2(vA, vB, sc);
                        mn = min8f(vA, vB);
                    }
                    *(f32x4*)(pp + (cc << 8) + ppA) = vA;
                    *(f32x4*)(pp + (cc << 8) + ppB) = vB;
                }
                __syncthreads();
                if (k < 3) { const float* nsrc = srow + ((((cc + 1) & 3)) << 8); ISSUE2(vA, vB, nsrc); }
                // ---- FMA chunk cc (next chunk's loads fly underneath) ----
#pragma unroll
                for (int l = 0; l < 8; ++l) {
                    const int jjg = (cc << 3) + l;
                    const int j = (jjg << 5) + jc;
                    const f32x4 wv = *(const f32x4*)&w_s[(j << 5) + (((hp + j) & 7) << 2)];
                    const int phij = (jjg << 5) + ((((jc >> 2) + jjg) & 7) << 2) + (jc & 3);
                    float pv[8];
#pragma unroll
                    for (int b = 0; b < 8; ++b) pv[b] = pp[(b << 10) + phij];  // broadcast reads
#pragma unroll
                    for (int b = 0; b < 8; ++b) {
                        acc[0][b] = fmaf(wv[0], pv[b], acc[0][b]);
                        acc[1][b] = fmaf(wv[1], pv[b], acc[1][b]);
                        acc[2][b] = fmaf(wv[2], pv[b], acc[2][b]);
                        acc[3][b] = fmaf(wv[3], pv[b], acc[3][b]);
                    }
                }
                cc = (cc + 1) & 3;
            }
            __syncthreads();   // all FMA pp-reads done; reuse pp as partial buffer
#pragma unroll
            for (int i = 0; i < 4; ++i)
#pragma unroll
                for (int b = 0; b < 8; ++b) {
                    const int oo = ((hp << 2) + i) * 8 + b;
                    pp[(oo << 5) + ((jc + oo) & 31)] = acc[i][b];   // rotated: conflict-free
                }
            __syncthreads();
#pragma unroll
            for (int k = 0; k < 32; ++k)
                red += pp[(tid << 5) + ((k + tid) & 31)];
        }
        const float tot = uval + red + ((t > 0) ? bias_eff : bias0);
        state = fmaf(a, tot - state, state);
        const float ov = tanhf(state);
        // tagged write-through store (L2 + IC): both the data AND the sync signal
        __hip_atomic_store(my_hist + ((size_t)t << 10), ov + 2.0f, __ATOMIC_RELAXED,
                           __HIP_MEMORY_SCOPE_AGENT);
        // issue next step's first chunk now: latency overlaps barrier + next poll window
        { const float* nsrc = sbase + ((size_t)t << 10) + (cbase << 8); ISSUE2(vA, vB, nsrc); }
        __syncthreads();   // protects pp: reduce-reads (this t) vs stage-writes (t+1)
    }
}

// ---------------- rnn_activity copy: act[t][b][h] = hist[b][t][h] - 2 (untag) ----------------
__global__ void copy_act(const float* __restrict__ hist, float* __restrict__ act) {
    const int t = blockIdx.x >> 6, b = blockIdx.x & 63;
    const float* src = hist + ((size_t)b * T_STEPS + t) * 1024 + threadIdx.x * 4;
    float* dst = act + ((size_t)t * BATCH + b) * 1024 + threadIdx.x * 4;
    float4 v = *(const float4*)src;
    v.x -= 2.0f; v.y -= 2.0f; v.z -= 2.0f; v.w -= 2.0f;
    *(float4*)dst = v;
}

// ---------------- final FC: out0[t][b][o] = (hist-2)[b][t][:819]@w_fc[o,:] + b_fc[o] ----------
__global__ void fc_out(const float* __restrict__ hist, const float* __restrict__ w_fcp,
                       const float* __restrict__ badj, float* __restrict__ out0) {
    __shared__ float hs[16 * 820];   // 52.5 KB
    const int t = blockIdx.x >> 2, bq = blockIdx.x & 3, tid = threadIdx.x;
    const int b0 = bq << 4;
    for (int r = 0; r < 16; ++r) {
        const float* src = hist + ((size_t)(b0 + r) * T_STEPS + t) * 1024;
        for (int e = tid; e < 820; e += 256) hs[r * 820 + e] = (e < ESZ) ? src[e] : 0.f;
    }
    __syncthreads();
    const int bb = tid >> 4, ol = tid & 15;
    float acc[4] = {0.f, 0.f, 0.f, 0.f};
    const float* hrow = hs + bb * 820;
    for (int e = 0; e < 820; e += 4) {
        const float4 hv = *(const float4*)(hrow + e);
#pragma unroll
        for (int k = 0; k < 4; ++k) {
            const float4 wv = *(const float4*)(w_fcp + (size_t)(ol + (k << 4)) * 820 + e);
            acc[k] += hv.x * wv.x + hv.y * wv.y + hv.z * wv.z + hv.w * wv.w;
        }
    }
    const int b = b0 + bb;
#pragma unroll
    for (int k = 0; k < 4; ++k) {
        const int o = ol + (k << 4);
        out0[((size_t)t * BATCH + b) * OSZ + o] = acc[k] + badj[o];
    }
}

extern "C" void kernel_launch(void* const* d_in, const int* in_sizes, int n_in,
                              void* d_out, int out_size, void* d_ws, size_t ws_size,
                              hipStream_t stream) {
    const float* x     = (const float*)d_in[0];
    const float* w_ih  = (const float*)d_in[1];
    const float* b_ih  = (const float*)d_in[2];
    const float* w_hh  = (const float*)d_in[3];
    const float* b_hh  = (const float*)d_in[4];
    const float* w_fc  = (const float*)d_in[5];
    const float* b_fc  = (const float*)d_in[6];
    const float* alpha = (const float*)d_in[7];
    const float* mask  = (const float*)d_in[8];

    float* out  = (float*)d_out;
    float* out0 = out;                                 // [512][64][64]
    float* act  = out + (size_t)T_STEPS * BATCH * OSZ; // [512][64][1024]

    float* ws     = (float*)d_ws;
    float* eff_w  = ws + WS_EFFW;
    float* w_ihT  = ws + WS_WIHT;
    float* hist   = ws + WS_HIST;
    float* badj   = ws + WS_BADJ;
    float* w_fcp  = ws + WS_WFCP;
    float* u      = act;   // inp_proj lives in d_out's activity region ([b][t][h]), overwritten later

    // hist must be zero so the [1,3]-range tag test distinguishes written from unwritten
    // (and so stale tagged values from a previous rep can't pass the poll).
    hipMemsetAsync(hist, 0, (size_t)BATCH * T_STEPS * HID * sizeof(float), stream);
    prep_effw<<<1024, 256, 0, stream>>>(w_hh, mask, eff_w);
    prep_wihT<<<512, 256, 0, stream>>>(w_ih, w_ihT);
    prep_wfc<<<64, 256, 0, stream>>>(w_fc, b_fc, w_fcp, badj);
    inp_proj<<<512, 256, 0, stream>>>(x, w_ihT, b_ih, u);

    hipFuncSetAttribute(reinterpret_cast<const void*>(rnn_scan),
                        hipFuncAttributeMaxDynamicSharedMemorySize, 163840);
    void* args[] = {(void*)&eff_w, (void*)&u, (void*)&b_hh, (void*)&alpha, (void*)&hist};
    hipLaunchCooperativeKernel(reinterpret_cast<const void*>(rnn_scan),
                               dim3(256), dim3(256), args, 163840, stream);

    copy_act<<<32768, 256, 0, stream>>>(hist, act);
    fc_out<<<2048, 256, 0, stream>>>(hist, w_fcp, badj, out0);
}